// Round 5
// baseline (162.991 us; speedup 1.0000x reference)
//
#include <hip/hip_runtime.h>
#include <stdint.h>

typedef unsigned short u16;
typedef __attribute__((ext_vector_type(8))) short short8;   // 8 x bf16 (4 VGPRs)
typedef __attribute__((ext_vector_type(4))) float f32x4;    // 4 x fp32 acc

typedef __attribute__((address_space(3))) uint8_t* lds_ptr_t;
typedef const __attribute__((address_space(1))) uint8_t* gbl_ptr_t;

__device__ __forceinline__ u16 f2bf(float f) {
    union { float f; uint32_t u; } v; v.f = f;
    return (u16)((v.u + (0x7FFFu + ((v.u >> 16) & 1u))) >> 16);   // RNE
}

// ---------------- P1+P2 merged: W2 = U*S (bf16) | Vp = MFMA-packed V -----------
__global__ void k_prep(const float* __restrict__ U, const float* __restrict__ S,
                       u16* __restrict__ W2,
                       const float* __restrict__ V, u16* __restrict__ Vp) {
    int bx = blockIdx.x;
    if (bx < 64) {
        int t = bx * 256 + threadIdx.x;                // 16384 threads
        int o = t >> 6, j = t & 63;
        float acc = 0.f;
#pragma unroll 8
        for (int i = 0; i < 64; ++i) acc += U[o * 64 + i] * S[i * 64 + j];
        W2[t] = f2bf(acc);
    } else {
        int t = (bx - 64) * 256 + threadIdx.x;         // 18432 threads (72 blocks)
        int ln = t & 63, mt = (t >> 6) & 3, cc = (t >> 8) & 1;
        int tap = (t >> 9) % 9, kv = t / 4608;
        int r = mt * 16 + (ln & 15);
        int cb = kv * 64 + cc * 32 + (ln >> 4) * 8;
        u16 tmp[8];
#pragma unroll
        for (int e = 0; e < 8; ++e)
            tmp[e] = f2bf(V[(size_t)((cb + e) * 9 + tap) * 64 + r]);
        *(uint4*)(Vp + (size_t)t * 8) = *(uint4*)tmp;
    }
}

// ---------------- P3: coalesced LDS-tiled transpose+pad  -----------------------
// xb[b][hp][wp][c] (bf16, [16][58][58][256]) from x[b][c][h][w] fp32.
__global__ __launch_bounds__(256) void k_tr(const float* __restrict__ x,
                                            u16* __restrict__ xb) {
    __shared__ uint32_t lds[64 * 57];               // 14592 B
    int bi = blockIdx.x;                            // 16*58*2 = 1856
    int cg = bi & 1;
    int hp = (bi >> 1) % 58;
    int b  = bi / 116;
    int c0 = cg * 128;
    int tid = threadIdx.x;

    uint32_t* xbrow32 = (uint32_t*)(xb + ((size_t)(b * 58 + hp) * 58) * 256 + c0);

    if (hp == 0 || hp == 57) {                      // border row: all zeros
        for (int i = tid; i < 58 * 64; i += 256)
            xbrow32[(i >> 6) * 128 + (i & 63)] = 0u;
        return;
    }

    int h = hp - 1;
    int w = tid & 63;                               // 56 valid
    int cpq = tid >> 6;                             // 0..3
    const float* xbase = x + ((size_t)(b * 256 + c0) * 3136) + h * 56 + w;
    if (w < 56) {
#pragma unroll
        for (int k = 0; k < 16; ++k) {
            int cp = cpq * 16 + k;                  // channel pair 0..63
            float a0 = xbase[(size_t)(2 * cp) * 3136];
            float a1 = xbase[(size_t)(2 * cp + 1) * 3136];
            lds[cp * 57 + w] = (uint32_t)f2bf(a0) | ((uint32_t)f2bf(a1) << 16);
        }
    }
    __syncthreads();

    int cpair = tid & 63;
    int wpq = tid >> 6;
#pragma unroll
    for (int wp = wpq; wp < 58; wp += 4) {
        uint32_t v = (wp == 0 || wp == 57) ? 0u : lds[cpair * 57 + (wp - 1)];
        xbrow32[wp * 128 + cpair] = v;
    }
}

// ---------------- Stage A v9: small-tile high-occupancy conv + fused W2 --------
// DIAGNOSIS (r0-r4): every 8x8-tile variant (shared/private/no stage, barriers
// or not) sits at MfmaUtil 9-11%, Occupancy ~16% -- the 51.2KB/784-block
// envelope caps residency at ~1-2 blocks/CU, so all latency is exposed.
// v9 shrinks the envelope: 4x8 tile, 6x10x256c window = 30.7KB LDS ->
// 1568 blocks, 5 blocks/CU (20 waves/CU) = 2.5x latency-hiding TLP.
// Keeps: v4's redundant shared stage (only fast-measured variant), XOR slot
// swizzle, 4-way K-split, fused W2 GEMM epilogue, XCD-chunked swizzle.
__global__ __launch_bounds__(256, 5) void k_conv(const u16* __restrict__ xb,
                                                 const u16* __restrict__ Vp,
                                                 const u16* __restrict__ W2,
                                                 const float* __restrict__ bias,
                                                 float* __restrict__ out) {
    __shared__ u16 lds[60 * 256];                   // 30720 B: [cell][512B swizzled]
    int bi0 = blockIdx.x;                           // 1568 = 8 * 196
    int bi = (bi0 & 7) * 196 + (bi0 >> 3);          // XCD-chunked swizzle
    int wt = bi % 7, ht = (bi / 7) % 14, b = bi / 98;
    int h0 = ht * 4, w0 = wt * 8;
    int tid = threadIdx.x;
    int kv = tid >> 6, ln = tid & 63;
    int lane15 = ln & 15, quad = ln >> 4;

    // ---- stage: 30 instrs x 1KB (all 4 waves, v4 redundant pattern);
    //      lane j of cell fetches slice (j ^ (cell&7)); 60 cells of 512B ----
    {
        int cs2 = ln >> 5;                          // which of the 2 cells/instr
        int j   = ln & 31;
        int cell = cs2, rr = 0, wp = cs2;
        const u16* gw = xb + (((size_t)(b * 58 + h0)) * 58 + w0) * 256;
        char* lb = (char*)lds;
        for (int i = 0; i < 30; ++i) {
            const u16* g = gw + (rr * 58 + wp) * 256 + ((j ^ (cell & 7)) << 3);
            __builtin_amdgcn_global_load_lds((gbl_ptr_t)g,
                                             (lds_ptr_t)(lb + i * 1024), 16, 0, 0);
            cell += 2; wp += 2;
            int wrap = (wp >= 10) ? 1 : 0;
            wp -= wrap * 10; rr += wrap;
        }
    }
    __syncthreads();

    // ---- K-loop: 9 taps x 2 cc (32c each) = 18 k-steps, 8 MFMA each ----
    int dh = lane15 >> 3, dw = lane15 & 7;          // dh 0..1, dw 0..7
    int jbase = (kv << 3) + quad;                   // j' = kv*8 + cc*4 + quad
    const char* lb = (const char*)lds;

    f32x4 acc[4][2];
#pragma unroll
    for (int mt = 0; mt < 4; ++mt)
#pragma unroll
        for (int nt = 0; nt < 2; ++nt) acc[mt][nt] = (f32x4){0.f, 0.f, 0.f, 0.f};

#pragma unroll
    for (int tap = 0; tap < 9; ++tap) {
        const int di = tap / 3, dj = tap % 3;
#pragma unroll
        for (int cc = 0; cc < 2; ++cc) {
            const u16* ab = Vp + ((size_t)(((kv * 9 + tap) * 2 + cc) * 4) * 512)
                          + ln * 8;
            short8 a[4];
#pragma unroll
            for (int mt = 0; mt < 4; ++mt)
                a[mt] = *(const short8*)(ab + mt * 512);
            int jj = jbase + (cc << 2);
            short8 bv[2];
#pragma unroll
            for (int nt = 0; nt < 2; ++nt) {
                int cell = (nt * 2 + dh + di) * 10 + (dw + dj);
                int off = cell * 512 + ((jj ^ (cell & 7)) << 4);
                bv[nt] = *(const short8*)(lb + off);
            }
#pragma unroll
            for (int mt = 0; mt < 4; ++mt)
#pragma unroll
                for (int nt = 0; nt < 2; ++nt)
                    acc[mt][nt] = __builtin_amdgcn_mfma_f32_16x16x32_bf16(
                        a[mt], bv[nt], acc[mt][nt], 0, 0, 0);
        }
    }

    // ---- 4-way K-split reduction into wave 0 (reuse LDS) ----
    __syncthreads();                                // all ds_reads of x done
    f32x4* red = (f32x4*)lds;                       // bytes [0, 16384)
    u16* y1l = lds + 8192;                          // bytes [16384, 20992): [32][72]
    if (kv & 1) {                                   // kv 1 -> red[0..7], 3 -> [8..15]
        f32x4* dst = red + ((kv >> 1) * 8) * 64;
#pragma unroll
        for (int f = 0; f < 8; ++f) dst[f * 64 + ln] = acc[f >> 1][f & 1];
    }
    __syncthreads();
    if (kv == 0) {
#pragma unroll
        for (int f = 0; f < 8; ++f) acc[f >> 1][f & 1] += red[f * 64 + ln];
    } else if (kv == 2) {
#pragma unroll
        for (int f = 0; f < 8; ++f) red[(8 + f) * 64 + ln] += acc[f >> 1][f & 1];
    }
    __syncthreads();
    if (kv == 0) {                                  // y1 tile -> LDS as bf16 [p][r]
#pragma unroll
        for (int mt = 0; mt < 4; ++mt)
#pragma unroll
            for (int nt = 0; nt < 2; ++nt) {
                f32x4 v = acc[mt][nt] + red[(8 + mt * 2 + nt) * 64 + ln];
                uint2 pv;
                pv.x = (uint32_t)f2bf(v[0]) | ((uint32_t)f2bf(v[1]) << 16);
                pv.y = (uint32_t)f2bf(v[2]) | ((uint32_t)f2bf(v[3]) << 16);
                // pixel p = nt*16+lane15, r = mt*16 + quad*4 .. +3
                *(uint2*)&y1l[(nt * 16 + lane15) * 72 + mt * 16 + quad * 4] = pv;
            }
    }
    __syncthreads();

    // ---- fused W2 GEMM: out[o][p] = sum_r W2[o][r] * y1[p][r] + bias[o] ----
    f32x4 acc2[4][2];
#pragma unroll
    for (int mt = 0; mt < 4; ++mt)
#pragma unroll
        for (int nt = 0; nt < 2; ++nt) acc2[mt][nt] = (f32x4){0.f, 0.f, 0.f, 0.f};

    int o0 = kv << 6;                               // wave kv owns o in [kv*64, +64)
#pragma unroll
    for (int ks = 0; ks < 64; ks += 32) {
        short8 a[4];
#pragma unroll
        for (int mt = 0; mt < 4; ++mt)
            a[mt] = *(const short8*)(W2 + (size_t)(o0 + mt * 16 + lane15) * 64
                                     + ks + quad * 8);
#pragma unroll
        for (int nt = 0; nt < 2; ++nt) {
            short8 bv = *(const short8*)&y1l[(nt * 16 + lane15) * 72 + ks + quad * 8];
#pragma unroll
            for (int mt = 0; mt < 4; ++mt)
                acc2[mt][nt] = __builtin_amdgcn_mfma_f32_16x16x32_bf16(
                    a[mt], bv, acc2[mt][nt], 0, 0, 0);
        }
    }

    // store: acc2[mt][nt][reg]: o = o0+mt*16+quad*4+reg, pixel p = nt*16+lane15
    //        -> oh = nt*2+dh (0..3), ow = dw
#pragma unroll
    for (int mt = 0; mt < 4; ++mt) {
        int ob = o0 + mt * 16 + quad * 4;
#pragma unroll
        for (int reg = 0; reg < 4; ++reg) {
            int o = ob + reg;
            float bvl = bias[o];
            float* orow = out + ((size_t)(b * 256 + o)) * 3136
                        + (h0 + dh) * 56 + (w0 + dw);
#pragma unroll
            for (int nt = 0; nt < 2; ++nt)
                orow[nt * 112] = acc2[mt][nt][reg] + bvl;   // nt*2 rows of 56
        }
    }
}

extern "C" void kernel_launch(void* const* d_in, const int* in_sizes, int n_in,
                              void* d_out, int out_size, void* d_ws, size_t ws_size,
                              hipStream_t stream) {
    const float* x    = (const float*)d_in[0];   // [16,256,56,56]
    const float* U    = (const float*)d_in[1];   // [256,64]
    const float* S    = (const float*)d_in[2];   // [64,64]
    const float* V    = (const float*)d_in[3];   // [2304,64]
    const float* bias = (const float*)d_in[4];   // [256]
    float* out = (float*)d_out;                  // [16,256,56,56] fp32

    char* ws = (char*)d_ws;
    u16* xb = (u16*)ws;                                   // 27,557,888 B
    u16* Vp = (u16*)(ws + 27557888);                      //    294,912 B
    u16* W2 = (u16*)(ws + 27557888 + 294912);             //     32,768 B

    k_prep <<<136,  256, 0, stream>>>(U, S, W2, V, Vp);
    k_tr   <<<1856, 256, 0, stream>>>(x, xb);
    k_conv <<<1568, 256, 0, stream>>>(xb, Vp, W2, bias, out);
}

// Round 6
// 159.128 us; speedup vs baseline: 1.0243x; 1.0243x over previous
//
#include <hip/hip_runtime.h>
#include <stdint.h>

typedef unsigned short u16;
typedef __attribute__((ext_vector_type(8))) short short8;   // 8 x bf16 (4 VGPRs)
typedef __attribute__((ext_vector_type(4))) float f32x4;    // 4 x fp32 acc

typedef __attribute__((address_space(3))) uint8_t* lds_ptr_t;
typedef const __attribute__((address_space(1))) uint8_t* gbl_ptr_t;

__device__ __forceinline__ u16 f2bf(float f) {
    union { float f; uint32_t u; } v; v.f = f;
    return (u16)((v.u + (0x7FFFu + ((v.u >> 16) & 1u))) >> 16);   // RNE
}

// ---------------- P1+P2 merged: W2 = U*S (bf16) | Vp = MFMA-packed V -----------
__global__ void k_prep(const float* __restrict__ U, const float* __restrict__ S,
                       u16* __restrict__ W2,
                       const float* __restrict__ V, u16* __restrict__ Vp) {
    int bx = blockIdx.x;
    if (bx < 64) {
        int t = bx * 256 + threadIdx.x;                // 16384 threads
        int o = t >> 6, j = t & 63;
        float acc = 0.f;
#pragma unroll 8
        for (int i = 0; i < 64; ++i) acc += U[o * 64 + i] * S[i * 64 + j];
        W2[t] = f2bf(acc);
    } else {
        int t = (bx - 64) * 256 + threadIdx.x;         // 18432 threads (72 blocks)
        int ln = t & 63, mt = (t >> 6) & 3, cc = (t >> 8) & 1;
        int tap = (t >> 9) % 9, kv = t / 4608;
        int r = mt * 16 + (ln & 15);
        int cb = kv * 64 + cc * 32 + (ln >> 4) * 8;
        u16 tmp[8];
#pragma unroll
        for (int e = 0; e < 8; ++e)
            tmp[e] = f2bf(V[(size_t)((cb + e) * 9 + tap) * 64 + r]);
        *(uint4*)(Vp + (size_t)t * 8) = *(uint4*)tmp;
    }
}

// ---------------- P3: coalesced LDS-tiled transpose+pad  -----------------------
// xb[b][hp][wp][c] (bf16, [16][58][58][256]) from x[b][c][h][w] fp32.
__global__ __launch_bounds__(256) void k_tr(const float* __restrict__ x,
                                            u16* __restrict__ xb) {
    __shared__ uint32_t lds[64 * 57];               // 14592 B
    int bi = blockIdx.x;                            // 16*58*2 = 1856
    int cg = bi & 1;
    int hp = (bi >> 1) % 58;
    int b  = bi / 116;
    int c0 = cg * 128;
    int tid = threadIdx.x;

    uint32_t* xbrow32 = (uint32_t*)(xb + ((size_t)(b * 58 + hp) * 58) * 256 + c0);

    if (hp == 0 || hp == 57) {                      // border row: all zeros
        for (int i = tid; i < 58 * 64; i += 256)
            xbrow32[(i >> 6) * 128 + (i & 63)] = 0u;
        return;
    }

    int h = hp - 1;
    int w = tid & 63;                               // 56 valid
    int cpq = tid >> 6;                             // 0..3
    const float* xbase = x + ((size_t)(b * 256 + c0) * 3136) + h * 56 + w;
    if (w < 56) {
#pragma unroll
        for (int k = 0; k < 16; ++k) {
            int cp = cpq * 16 + k;                  // channel pair 0..63
            float a0 = xbase[(size_t)(2 * cp) * 3136];
            float a1 = xbase[(size_t)(2 * cp + 1) * 3136];
            lds[cp * 57 + w] = (uint32_t)f2bf(a0) | ((uint32_t)f2bf(a1) << 16);
        }
    }
    __syncthreads();

    int cpair = tid & 63;
    int wpq = tid >> 6;
#pragma unroll
    for (int wp = wpq; wp < 58; wp += 4) {
        uint32_t v = (wp == 0 || wp == 57) ? 0u : lds[cpair * 57 + (wp - 1)];
        xbrow32[wp * 128 + cpair] = v;
    }
}

// ---------------- Stage A v10: occupancy x ILP conv + fused W2 -----------------
// DIAGNOSIS r5: v9's lb(256,5) forced VGPR<=64 (allocator hit 48) -> compiler
// serialized each k-step (load A -> wait -> load bv -> wait -> 8 MFMA), ~400cy
// exposed L2 latency per step, duty ~9% == measured MfmaUtil. v7/v8 had regs
// but no occupancy; v9 had occupancy but no regs. v10 has BOTH:
//   - lb(256,4): VGPR cap 128 (LDS 30.7KB still allows 4 blocks/CU = 16 waves)
//   - explicit 2-stage software pipeline: step s+1's 4 A-loads + 2 bv ds_reads
//     issued before step s's MFMAs (a0/a1, b0/b1 rotation; all indices static
//     after full unroll). s=0 A-frags issued BEFORE the stage barrier.
__global__ __launch_bounds__(256, 4) void k_conv(const u16* __restrict__ xb,
                                                 const u16* __restrict__ Vp,
                                                 const u16* __restrict__ W2,
                                                 const float* __restrict__ bias,
                                                 float* __restrict__ out) {
    __shared__ u16 lds[60 * 256];                   // 30720 B: [cell][512B swizzled]
    int bi0 = blockIdx.x;                           // 1568 = 8 * 196
    int bi = (bi0 & 7) * 196 + (bi0 >> 3);          // XCD-chunked swizzle
    int wt = bi % 7, ht = (bi / 7) % 14, b = bi / 98;
    int h0 = ht * 4, w0 = wt * 8;
    int tid = threadIdx.x;
    int kv = tid >> 6, ln = tid & 63;
    int lane15 = ln & 15, quad = ln >> 4;

    // ---- stage: 30 instrs x 1KB (all 4 waves, v4 redundant pattern);
    //      lane j of cell fetches slice (j ^ (cell&7)); 60 cells of 512B ----
    {
        int cs2 = ln >> 5;                          // which of the 2 cells/instr
        int j   = ln & 31;
        int cell = cs2, rr = 0, wp = cs2;
        const u16* gw = xb + (((size_t)(b * 58 + h0)) * 58 + w0) * 256;
        char* lb = (char*)lds;
        for (int i = 0; i < 30; ++i) {
            const u16* g = gw + (rr * 58 + wp) * 256 + ((j ^ (cell & 7)) << 3);
            __builtin_amdgcn_global_load_lds((gbl_ptr_t)g,
                                             (lds_ptr_t)(lb + i * 1024), 16, 0, 0);
            cell += 2; wp += 2;
            int wrap = (wp >= 10) ? 1 : 0;
            wp -= wrap * 10; rr += wrap;
        }
    }

    int dh = lane15 >> 3, dw = lane15 & 7;          // dh 0..1, dw 0..7
    int jbase = (kv << 3) + quad;                   // j' = kv*8 + cc*4 + quad
    const char* lb = (const char*)lds;
    const u16* apb = Vp + ((size_t)(kv * 72)) * 512 + ln * 8;

    f32x4 acc[4][2];
#pragma unroll
    for (int mt = 0; mt < 4; ++mt)
#pragma unroll
        for (int nt = 0; nt < 2; ++nt) acc[mt][nt] = (f32x4){0.f, 0.f, 0.f, 0.f};

    short8 a0[4], a1[4], b0[2], b1[2];
    // s=0 A-frags issued before the barrier (independent of LDS; the barrier's
    // implicit vmcnt(0) drains them into regs for free).
#pragma unroll
    for (int mt = 0; mt < 4; ++mt)
        a0[mt] = *(const short8*)(apb + (size_t)mt * 512);
    __syncthreads();

    // s=0 bv (tap0 -> di=0,dj=0; cc=0 -> jj=jbase)
#pragma unroll
    for (int nt = 0; nt < 2; ++nt) {
        int cell = (nt * 2 + dh) * 10 + dw;
        b0[nt] = *(const short8*)(lb + cell * 512 + ((jbase ^ (cell & 7)) << 4));
    }

    // ---- pipelined K-loop: 18 steps (tap = s>>1, cc = s&1), 8 MFMA each ----
#pragma unroll
    for (int s = 0; s < 18; ++s) {
        if (s < 17) {                               // prefetch step s+1
            const int sn = s + 1, tn = sn >> 1, cn = sn & 1;
            const int di = tn / 3, dj = tn % 3;
            const int jj = jbase + (cn << 2);
            const u16* ab = apb + ((size_t)((tn * 2 + cn) * 4)) * 512;
#pragma unroll
            for (int mt = 0; mt < 4; ++mt) {
                short8 v = *(const short8*)(ab + mt * 512);
                if (s & 1) a0[mt] = v; else a1[mt] = v;
            }
#pragma unroll
            for (int nt = 0; nt < 2; ++nt) {
                int cell = (nt * 2 + dh + di) * 10 + (dw + dj);
                short8 v = *(const short8*)(lb + cell * 512
                                            + ((jj ^ (cell & 7)) << 4));
                if (s & 1) b0[nt] = v; else b1[nt] = v;
            }
        }
#pragma unroll
        for (int mt = 0; mt < 4; ++mt)
#pragma unroll
            for (int nt = 0; nt < 2; ++nt)
                acc[mt][nt] = __builtin_amdgcn_mfma_f32_16x16x32_bf16(
                    (s & 1) ? a1[mt] : a0[mt],
                    (s & 1) ? b1[nt] : b0[nt],
                    acc[mt][nt], 0, 0, 0);
    }

    // ---- 4-way K-split reduction into wave 0 (reuse LDS) ----
    __syncthreads();                                // all ds_reads of x done
    f32x4* red = (f32x4*)lds;                       // bytes [0, 16384)
    u16* y1l = lds + 8192;                          // bytes [16384, 20992): [32][72]
    if (kv & 1) {                                   // kv 1 -> red[0..7], 3 -> [8..15]
        f32x4* dst = red + ((kv >> 1) * 8) * 64;
#pragma unroll
        for (int f = 0; f < 8; ++f) dst[f * 64 + ln] = acc[f >> 1][f & 1];
    }
    __syncthreads();
    if (kv == 0) {
#pragma unroll
        for (int f = 0; f < 8; ++f) acc[f >> 1][f & 1] += red[f * 64 + ln];
    } else if (kv == 2) {
#pragma unroll
        for (int f = 0; f < 8; ++f) red[(8 + f) * 64 + ln] += acc[f >> 1][f & 1];
    }
    __syncthreads();
    if (kv == 0) {                                  // y1 tile -> LDS as bf16 [p][r]
#pragma unroll
        for (int mt = 0; mt < 4; ++mt)
#pragma unroll
            for (int nt = 0; nt < 2; ++nt) {
                f32x4 v = acc[mt][nt] + red[(8 + mt * 2 + nt) * 64 + ln];
                uint2 pv;
                pv.x = (uint32_t)f2bf(v[0]) | ((uint32_t)f2bf(v[1]) << 16);
                pv.y = (uint32_t)f2bf(v[2]) | ((uint32_t)f2bf(v[3]) << 16);
                // pixel p = nt*16+lane15, r = mt*16 + quad*4 .. +3
                *(uint2*)&y1l[(nt * 16 + lane15) * 72 + mt * 16 + quad * 4] = pv;
            }
    }
    __syncthreads();

    // ---- fused W2 GEMM: out[o][p] = sum_r W2[o][r] * y1[p][r] + bias[o] ----
    f32x4 acc2[4][2];
#pragma unroll
    for (int mt = 0; mt < 4; ++mt)
#pragma unroll
        for (int nt = 0; nt < 2; ++nt) acc2[mt][nt] = (f32x4){0.f, 0.f, 0.f, 0.f};

    int o0 = kv << 6;                               // wave kv owns o in [kv*64, +64)
#pragma unroll
    for (int ks = 0; ks < 64; ks += 32) {
        short8 a[4];
#pragma unroll
        for (int mt = 0; mt < 4; ++mt)
            a[mt] = *(const short8*)(W2 + (size_t)(o0 + mt * 16 + lane15) * 64
                                     + ks + quad * 8);
#pragma unroll
        for (int nt = 0; nt < 2; ++nt) {
            short8 bv = *(const short8*)&y1l[(nt * 16 + lane15) * 72 + ks + quad * 8];
#pragma unroll
            for (int mt = 0; mt < 4; ++mt)
                acc2[mt][nt] = __builtin_amdgcn_mfma_f32_16x16x32_bf16(
                    a[mt], bv, acc2[mt][nt], 0, 0, 0);
        }
    }

    // store: acc2[mt][nt][reg]: o = o0+mt*16+quad*4+reg, pixel p = nt*16+lane15
    //        -> oh = nt*2+dh (0..3), ow = dw
#pragma unroll
    for (int mt = 0; mt < 4; ++mt) {
        int ob = o0 + mt * 16 + quad * 4;
#pragma unroll
        for (int reg = 0; reg < 4; ++reg) {
            int o = ob + reg;
            float bvl = bias[o];
            float* orow = out + ((size_t)(b * 256 + o)) * 3136
                        + (h0 + dh) * 56 + (w0 + dw);
#pragma unroll
            for (int nt = 0; nt < 2; ++nt)
                orow[nt * 112] = acc2[mt][nt][reg] + bvl;   // nt*2 rows of 56
        }
    }
}

extern "C" void kernel_launch(void* const* d_in, const int* in_sizes, int n_in,
                              void* d_out, int out_size, void* d_ws, size_t ws_size,
                              hipStream_t stream) {
    const float* x    = (const float*)d_in[0];   // [16,256,56,56]
    const float* U    = (const float*)d_in[1];   // [256,64]
    const float* S    = (const float*)d_in[2];   // [64,64]
    const float* V    = (const float*)d_in[3];   // [2304,64]
    const float* bias = (const float*)d_in[4];   // [256]
    float* out = (float*)d_out;                  // [16,256,56,56] fp32

    char* ws = (char*)d_ws;
    u16* xb = (u16*)ws;                                   // 27,557,888 B
    u16* Vp = (u16*)(ws + 27557888);                      //    294,912 B
    u16* W2 = (u16*)(ws + 27557888 + 294912);             //     32,768 B

    k_prep <<<136,  256, 0, stream>>>(U, S, W2, V, Vp);
    k_tr   <<<1856, 256, 0, stream>>>(x, xb);
    k_conv <<<1568, 256, 0, stream>>>(xb, Vp, W2, bias, out);
}

// Round 7
// 150.810 us; speedup vs baseline: 1.0808x; 1.0552x over previous
//
#include <hip/hip_runtime.h>
#include <stdint.h>

typedef unsigned short u16;
typedef __attribute__((ext_vector_type(8))) short short8;   // 8 x bf16 (4 VGPRs)
typedef __attribute__((ext_vector_type(4))) float f32x4;    // 4 x fp32 acc

typedef __attribute__((address_space(3))) uint8_t* lds_ptr_t;
typedef const __attribute__((address_space(1))) uint8_t* gbl_ptr_t;

__device__ __forceinline__ u16 f2bf(float f) {
    union { float f; uint32_t u; } v; v.f = f;
    return (u16)((v.u + (0x7FFFu + ((v.u >> 16) & 1u))) >> 16);   // RNE
}

// ---------------- P1+P2 merged: W2 = U*S (bf16) | Vp = MFMA-packed V -----------
// (validated rounds 2-6; identical outputs to the original k_us/k_vpack pair)
__global__ void k_prep(const float* __restrict__ U, const float* __restrict__ S,
                       u16* __restrict__ W2,
                       const float* __restrict__ V, u16* __restrict__ Vp) {
    int bx = blockIdx.x;
    if (bx < 64) {
        int t = bx * 256 + threadIdx.x;                // 16384 threads
        int o = t >> 6, j = t & 63;
        float acc = 0.f;
#pragma unroll 8
        for (int i = 0; i < 64; ++i) acc += U[o * 64 + i] * S[i * 64 + j];
        W2[t] = f2bf(acc);
    } else {
        int t = (bx - 64) * 256 + threadIdx.x;         // 18432 threads (72 blocks)
        int ln = t & 63, mt = (t >> 6) & 3, cc = (t >> 8) & 1;
        int tap = (t >> 9) % 9, kv = t / 4608;
        int r = mt * 16 + (ln & 15);
        int cb = kv * 64 + cc * 32 + (ln >> 4) * 8;
        u16 tmp[8];
#pragma unroll
        for (int e = 0; e < 8; ++e)
            tmp[e] = f2bf(V[(size_t)((cb + e) * 9 + tap) * 64 + r]);
        *(uint4*)(Vp + (size_t)t * 8) = *(uint4*)tmp;
    }
}

// ---------------- P3: coalesced LDS-tiled transpose+pad  -----------------------
// xb[b][hp][wp][c] (bf16, [16][58][58][256]) from x[b][c][h][w] fp32.
__global__ __launch_bounds__(256) void k_tr(const float* __restrict__ x,
                                            u16* __restrict__ xb) {
    __shared__ uint32_t lds[64 * 57];               // 14592 B
    int bi = blockIdx.x;                            // 16*58*2 = 1856
    int cg = bi & 1;
    int hp = (bi >> 1) % 58;
    int b  = bi / 116;
    int c0 = cg * 128;
    int tid = threadIdx.x;

    uint32_t* xbrow32 = (uint32_t*)(xb + ((size_t)(b * 58 + hp) * 58) * 256 + c0);

    if (hp == 0 || hp == 57) {                      // border row: all zeros
        for (int i = tid; i < 58 * 64; i += 256)
            xbrow32[(i >> 6) * 128 + (i & 63)] = 0u;
        return;
    }

    int h = hp - 1;
    int w = tid & 63;                               // 56 valid
    int cpq = tid >> 6;                             // 0..3
    const float* xbase = x + ((size_t)(b * 256 + c0) * 3136) + h * 56 + w;
    if (w < 56) {
#pragma unroll
        for (int k = 0; k < 16; ++k) {
            int cp = cpq * 16 + k;                  // channel pair 0..63
            float a0 = xbase[(size_t)(2 * cp) * 3136];
            float a1 = xbase[(size_t)(2 * cp + 1) * 3136];
            lds[cp * 57 + w] = (uint32_t)f2bf(a0) | ((uint32_t)f2bf(a1) << 16);
        }
    }
    __syncthreads();

    int cpair = tid & 63;
    int wpq = tid >> 6;
#pragma unroll
    for (int wp = wpq; wp < 58; wp += 4) {
        uint32_t v = (wp == 0 || wp == 57) ? 0u : lds[cpair * 57 + (wp - 1)];
        xbrow32[wp * 128 + cpair] = v;
    }
}

// ---------------- Stage A v11: round-0 v4 + stage-dedup ONLY -------------------
// Exact round-0 structure (8x8 tile, 784 blocks, 51.2KB window, lb(256,2),
// 18-kstep loop, 4-way K-split reduction, separate gemmB). ONE change:
// the 50 stage loads are split across the 4 waves (i = kv; i += 4) instead of
// all 4 waves redundantly issuing all 50 -- deletes 150 TA instructions/block
// (490 -> 340, -30%). Tests the "vector-memory issue path is the shared serial
// bottleneck" model against the best-known baseline with zero confounds.
__global__ __launch_bounds__(256, 2) void k_convA(const u16* __restrict__ xb,
                                                  const u16* __restrict__ Vp,
                                                  u16* __restrict__ y1) {
    __shared__ u16 lds[100 * 256];                  // 51200 B: [cell][512B swizzled]
    int bi = blockIdx.x;                            // 784
    int wt = bi % 7, ht = (bi / 7) % 7, b = bi / 49;
    int h0 = ht * 8, w0 = wt * 8;
    int tid = threadIdx.x;
    int kv = tid >> 6, ln = tid & 63;
    int lane15 = ln & 15, quad = ln >> 4;

    // ---- stage: 50 instrs x 1KB, split across waves (i = kv, kv+4, ...);
    //      lane j of cell fetches slice (j ^ (cell&7)) ----
    {
        int cs2 = ln >> 5;                          // which of the 2 cells/instr
        int j   = ln & 31;
        int cell = 2 * kv + cs2;
        int rr = 0, wp = cell;                      // cell <= 7 < 10
        const u16* gw = xb + (((size_t)(b * 58 + h0)) * 58 + w0) * 256;
        char* lb = (char*)lds;
        for (int i = kv; i < 50; i += 4) {
            const u16* g = gw + (rr * 58 + wp) * 256 + ((j ^ (cell & 7)) << 3);
            __builtin_amdgcn_global_load_lds((gbl_ptr_t)g,
                                             (lds_ptr_t)(lb + i * 1024), 16, 0, 0);
            cell += 8; wp += 8;
            if (wp >= 10) { wp -= 10; rr += 1; }
        }
    }
    __syncthreads();

    // ---- K-loop: 9 taps x 2 cc (32c each) = 18 MFMA k-steps, no barriers ----
    int dh = lane15 >> 3, dw = lane15 & 7;
    int cell00 = dh * 10 + dw;
    int jbase = (kv << 3) + quad;                   // j' = kv*8 + cc*4 + quad
    const char* lb = (const char*)lds;

    f32x4 acc[4][4];
#pragma unroll
    for (int mt = 0; mt < 4; ++mt)
#pragma unroll
        for (int nt = 0; nt < 4; ++nt) acc[mt][nt] = (f32x4){0.f, 0.f, 0.f, 0.f};

#pragma unroll
    for (int tap = 0; tap < 9; ++tap) {
        const int di = tap / 3, dj = tap % 3;
#pragma unroll
        for (int cc = 0; cc < 2; ++cc) {
            const u16* ab = Vp + ((size_t)(((kv * 9 + tap) * 2 + cc) * 4) * 512)
                          + ln * 8;
            short8 a[4];
#pragma unroll
            for (int mt = 0; mt < 4; ++mt)
                a[mt] = *(const short8*)(ab + mt * 512);
            int jj = jbase + (cc << 2);
            short8 bv[4];
#pragma unroll
            for (int nt = 0; nt < 4; ++nt) {
                int cell = cell00 + nt * 20 + di * 10 + dj;
                int off = cell * 512 + ((jj ^ (cell & 7)) << 4);
                bv[nt] = *(const short8*)(lb + off);
            }
#pragma unroll
            for (int mt = 0; mt < 4; ++mt)
#pragma unroll
                for (int nt = 0; nt < 4; ++nt)
                    acc[mt][nt] = __builtin_amdgcn_mfma_f32_16x16x32_bf16(
                        a[mt], bv[nt], acc[mt][nt], 0, 0, 0);
        }
    }

    // ---- 4-way K-split reduction (reuse x-LDS; 32KB <= 51.2KB) ----
    __syncthreads();                                // all ds_reads of x done
    f32x4* red = (f32x4*)lds;
    if (kv & 1) {                                   // kv 1 -> red[0..15], 3 -> [16..31]
        f32x4* dst = red + ((kv >> 1) * 16) * 64;
#pragma unroll
        for (int f = 0; f < 16; ++f) dst[f * 64 + ln] = acc[f >> 2][f & 3];
    }
    __syncthreads();
    if (kv == 0) {
#pragma unroll
        for (int f = 0; f < 16; ++f) acc[f >> 2][f & 3] += red[f * 64 + ln];
    } else if (kv == 2) {
#pragma unroll
        for (int f = 0; f < 16; ++f) red[(16 + f) * 64 + ln] += acc[f >> 2][f & 3];
    }
    __syncthreads();
    if (kv == 0) {
#pragma unroll
        for (int mt = 0; mt < 4; ++mt)
#pragma unroll
            for (int nt = 0; nt < 4; ++nt) {
                f32x4 v = acc[mt][nt] + red[(16 + mt * 4 + nt) * 64 + ln];
                int oh = nt * 2 + dh, ow = dw;
                int l = b * 3136 + (h0 + oh) * 56 + (w0 + ow);
                uint2 pv;
                pv.x = (uint32_t)f2bf(v[0]) | ((uint32_t)f2bf(v[1]) << 16);
                pv.y = (uint32_t)f2bf(v[2]) | ((uint32_t)f2bf(v[3]) << 16);
                *(uint2*)(y1 + ((size_t)l << 6) + mt * 16 + quad * 4) = pv;
            }
    }
}

// ---------------- Stage B: out[b][o][l] = W2[o][:] . y1[b][l][:] + bias[o] -----
__global__ __launch_bounds__(256) void k_gemmB(const u16* __restrict__ y1,
                                               const u16* __restrict__ W2,
                                               const float* __restrict__ bias,
                                               float* __restrict__ out) {
    __shared__ u16 lds_y[64 * 72];                  // 9216 B
    int bi = blockIdx.x;                            // 784 = 16*49
    int b = bi % 16, lt = bi / 16;
    int l0 = lt * 64;
    int tid = threadIdx.x;
    int wv = tid >> 6, ln = tid & 63;
    int lane15 = ln & 15, quad = ln >> 4;

    for (int idx = tid; idx < 512; idx += 256) {
        int q = idx & 7, n = idx >> 3;
        uint4 v = *(const uint4*)(y1 + (((size_t)(b * 3136 + l0 + n)) << 6) + q * 8);
        *(uint4*)&lds_y[n * 72 + q * 8] = v;
    }
    __syncthreads();

    f32x4 acc[4][4];
#pragma unroll
    for (int mt = 0; mt < 4; ++mt)
#pragma unroll
        for (int nt = 0; nt < 4; ++nt) acc[mt][nt] = (f32x4){0.f, 0.f, 0.f, 0.f};

    int o0 = wv * 64;
#pragma unroll
    for (int ks = 0; ks < 64; ks += 32) {
        short8 a[4];
#pragma unroll
        for (int mt = 0; mt < 4; ++mt)
            a[mt] = *(const short8*)(W2 + (size_t)(o0 + mt * 16 + lane15) * 64
                                     + ks + quad * 8);
#pragma unroll
        for (int nt = 0; nt < 4; ++nt) {
            short8 bv = *(const short8*)&lds_y[(nt * 16 + lane15) * 72 + ks + quad * 8];
#pragma unroll
            for (int mt = 0; mt < 4; ++mt)
                acc[mt][nt] = __builtin_amdgcn_mfma_f32_16x16x32_bf16(a[mt], bv, acc[mt][nt], 0, 0, 0);
        }
    }

#pragma unroll
    for (int mt = 0; mt < 4; ++mt) {
        int ob = o0 + mt * 16 + quad * 4;
#pragma unroll
        for (int reg = 0; reg < 4; ++reg) {
            int o = ob + reg;
            float bvl = bias[o];
            float* orow = out + ((size_t)(b * 256 + o)) * 3136 + l0 + lane15;
#pragma unroll
            for (int nt = 0; nt < 4; ++nt)
                orow[nt * 16] = acc[mt][nt][reg] + bvl;
        }
    }
}

extern "C" void kernel_launch(void* const* d_in, const int* in_sizes, int n_in,
                              void* d_out, int out_size, void* d_ws, size_t ws_size,
                              hipStream_t stream) {
    const float* x    = (const float*)d_in[0];   // [16,256,56,56]
    const float* U    = (const float*)d_in[1];   // [256,64]
    const float* S    = (const float*)d_in[2];   // [64,64]
    const float* V    = (const float*)d_in[3];   // [2304,64]
    const float* bias = (const float*)d_in[4];   // [256]
    float* out = (float*)d_out;                  // [16,256,56,56] fp32

    char* ws = (char*)d_ws;
    u16* xb = (u16*)ws;                                   // 27,557,888 B
    u16* Vp = (u16*)(ws + 27557888);                      //    294,912 B
    u16* W2 = (u16*)(ws + 27557888 + 294912);             //     32,768 B
    u16* y1 = (u16*)(ws + 27557888 + 294912 + 32768);     //  6,422,528 B

    k_prep <<<136,  256, 0, stream>>>(U, S, W2, V, Vp);
    k_tr   <<<1856, 256, 0, stream>>>(x, xb);
    k_convA<<<784,  256, 0, stream>>>(xb, Vp, y1);
    k_gemmB<<<784,  256, 0, stream>>>(y1, W2, bias, out);
}